// Round 1
// baseline (286.300 us; speedup 1.0000x reference)
//
#include <hip/hip_runtime.h>
#include <stdint.h>
#include <stddef.h>

typedef __bf16 bf16;
typedef bf16 bf16x4 __attribute__((ext_vector_type(4)));
typedef bf16 bf16x8 __attribute__((ext_vector_type(8)));
typedef float f32x4 __attribute__((ext_vector_type(4)));

#define DEVI static __device__ __forceinline__

// B=2, N=4096, DIM=512, HEADS=8, DHEAD=64, INNER=512
// M_ROWS = 8192, K = 512 for both GEMMs.

DEVI f32x4 mfma16(bf16x8 a, bf16x8 b, f32x4 c) {
  return __builtin_amdgcn_mfma_f32_16x16x32_bf16(a, b, c, 0, 0, 0);
}

DEVI void gload_lds16(const bf16* g, bf16* lds) {
  __builtin_amdgcn_global_load_lds(
      (const __attribute__((address_space(1))) unsigned int*)g,
      (__attribute__((address_space(3))) unsigned int*)lds, 16, 0, 0);
}

// ---------- f32 -> bf16 convert (vectorized) ----------
__global__ __launch_bounds__(256) void cvt_kernel(const float* __restrict__ in,
                                                  bf16* __restrict__ out, int n4) {
  int i = blockIdx.x * blockDim.x + threadIdx.x;
  const int stride = gridDim.x * blockDim.x;
  for (; i < n4; i += stride) {
    f32x4 v = reinterpret_cast<const f32x4*>(in)[i];
    bf16x4 o;
    o[0] = (bf16)v[0]; o[1] = (bf16)v[1]; o[2] = (bf16)v[2]; o[3] = (bf16)v[3];
    reinterpret_cast<bf16x4*>(out)[i] = o;
  }
}

// ---------- transpose-convert: in [K][N] f32 -> out [N][K] bf16 ----------
__global__ __launch_bounds__(256) void tcvt_kernel(const float* __restrict__ in,
                                                   bf16* __restrict__ out, int Kd, int Nd) {
  int i = blockIdx.x * blockDim.x + threadIdx.x;
  const int total = Kd * Nd;
  const int stride = gridDim.x * blockDim.x;
  for (; i < total; i += stride) {
    int k = i / Nd, n = i - k * Nd;
    out[(size_t)n * Kd + k] = (bf16)in[i];
  }
}

// ---------- GEMM: A[M][512] bf16 row-major, BT[N][512] bf16 row-major ----------
// 128x128 tile, BK=64, 4 waves (2x2), each wave 64x64 = 4x4 frags of 16x16x32.
// EPI 0: scatter to Q [bh][n][d], K [bh][n][d], VT [bh][d][n] as bf16 (qkv GEMM).
// EPI 1: out f32 [M][512] = acc + bias[col] (output projection).
template <int EPI>
__global__ __launch_bounds__(256) void gemm_kernel(
    const bf16* __restrict__ A, const bf16* __restrict__ BT,
    bf16* __restrict__ qo, bf16* __restrict__ ko, bf16* __restrict__ vto,
    const float* __restrict__ bias, float* __restrict__ fo) {
  constexpr int K = 512;
  __shared__ __align__(16) bf16 As[128 * 64];
  __shared__ __align__(16) bf16 Bs[128 * 64];
  const int lane = threadIdx.x & 63;
  const int w = threadIdx.x >> 6;
  const int wm = w >> 1, wn = w & 1;
  const int m0 = blockIdx.y * 128, n0 = blockIdx.x * 128;
  const int srow = lane >> 3, scol8 = (lane & 7) * 8;

  f32x4 acc[4][4];
#pragma unroll
  for (int i = 0; i < 4; ++i)
#pragma unroll
    for (int j = 0; j < 4; ++j) acc[i][j] = {0.f, 0.f, 0.f, 0.f};

  for (int kt = 0; kt < K / 64; ++kt) {
    const int k0 = kt * 64;
    __syncthreads();
#pragma unroll
    for (int c = 0; c < 4; ++c) {
      const int ca = w * 4 + c;          // 16 x 1KB calls per tile
      const int trow = ca * 8 + srow;    // tile row this lane covers
      gload_lds16(A + (size_t)(m0 + trow) * K + k0 + scol8, As + ca * 512);
      gload_lds16(BT + (size_t)(n0 + trow) * K + k0 + scol8, Bs + ca * 512);
    }
    __syncthreads();
#pragma unroll
    for (int kc = 0; kc < 2; ++kc) {
      bf16x8 af[4], bfr[4];
#pragma unroll
      for (int mi = 0; mi < 4; ++mi)
        af[mi] = *reinterpret_cast<const bf16x8*>(
            &As[(wm * 64 + mi * 16 + (lane & 15)) * 64 + kc * 32 + (lane >> 4) * 8]);
#pragma unroll
      for (int ni = 0; ni < 4; ++ni)
        bfr[ni] = *reinterpret_cast<const bf16x8*>(
            &Bs[(wn * 64 + ni * 16 + (lane & 15)) * 64 + kc * 32 + (lane >> 4) * 8]);
#pragma unroll
      for (int mi = 0; mi < 4; ++mi)
#pragma unroll
        for (int ni = 0; ni < 4; ++ni)
          acc[mi][ni] = mfma16(af[mi], bfr[ni], acc[mi][ni]);
    }
  }

#pragma unroll
  for (int mi = 0; mi < 4; ++mi) {
#pragma unroll
    for (int ni = 0; ni < 4; ++ni) {
#pragma unroll
      for (int r = 0; r < 4; ++r) {
        const int m = m0 + wm * 64 + mi * 16 + (lane >> 4) * 4 + r;
        const int col = n0 + wn * 64 + ni * 16 + (lane & 15);
        const float v = acc[mi][ni][r];
        if (EPI == 0) {
          const int b = m >> 12, n = m & 4095;
          const int sec = col >> 9, jj = col & 511, h = jj >> 6, d = jj & 63;
          const int bh = b * 8 + h;
          const bf16 hv = (bf16)v;
          if (sec == 0)
            qo[((size_t)bh * 4096 + n) * 64 + d] = hv;
          else if (sec == 1)
            ko[((size_t)bh * 4096 + n) * 64 + d] = hv;
          else
            vto[((size_t)bh * 64 + d) * 4096 + n] = hv;
        } else {
          fo[(size_t)m * 512 + col] = v + bias[col];
        }
      }
    }
  }
}

// ---------- fused relu-attention ----------
// grid (32 q-tiles, 16 bh). 4 waves/block; wave owns 32 q rows.
// Per kv-chunk of 64: stage K [64][64] and VT [64][64] in LDS, QK^T (MFMA),
// relu -> P (per-wave LDS buffer, D-layout write / A-layout read), PV (MFMA).
// scale deferred to the final O write (relu(s*c) = c*relu(s), c>0).
__global__ __launch_bounds__(256) void attn_kernel(
    const bf16* __restrict__ Q, const bf16* __restrict__ Kg,
    const bf16* __restrict__ VT, float* __restrict__ out) {
  __shared__ __align__(16) bf16 Ks[64 * 64];       // [kv][d]
  __shared__ __align__(16) bf16 Vs[64 * 64];       // [d][kv]
  __shared__ __align__(16) bf16 Ps[4][32 * 64];    // per-wave [q][kv]
  const int lane = threadIdx.x & 63;
  const int w = threadIdx.x >> 6;
  const int bh = blockIdx.y;
  const int q0 = blockIdx.x * 128 + w * 32;
  const bf16* Qh = Q + (size_t)bh * 4096 * 64;
  const bf16* Kh = Kg + (size_t)bh * 4096 * 64;
  const bf16* Vh = VT + (size_t)bh * 64 * 4096;

  bf16x8 qf[2][2];
#pragma unroll
  for (int qb = 0; qb < 2; ++qb)
#pragma unroll
    for (int kc = 0; kc < 2; ++kc)
      qf[qb][kc] = *reinterpret_cast<const bf16x8*>(
          &Qh[(size_t)(q0 + qb * 16 + (lane & 15)) * 64 + kc * 32 + (lane >> 4) * 8]);

  f32x4 o[2][4];
#pragma unroll
  for (int qb = 0; qb < 2; ++qb)
#pragma unroll
    for (int db = 0; db < 4; ++db) o[qb][db] = {0.f, 0.f, 0.f, 0.f};

  bf16* Pw = Ps[w];
  const int srow = lane >> 3, scol8 = (lane & 7) * 8;

  for (int kv0 = 0; kv0 < 4096; kv0 += 64) {
    __syncthreads();
    if (w < 2) {  // waves 0-1: K tile (rows contiguous in global)
#pragma unroll
      for (int c = 0; c < 4; ++c) {
        const int ca = w * 4 + c;
        gload_lds16(Kh + (size_t)kv0 * 64 + ca * 512 + lane * 8, Ks + ca * 512);
      }
    } else {  // waves 2-3: VT tile (row stride 4096 in global, per-lane source addr)
#pragma unroll
      for (int c = 0; c < 4; ++c) {
        const int ca = (w - 2) * 4 + c;
        const int d = ca * 8 + srow;
        gload_lds16(Vh + (size_t)d * 4096 + kv0 + scol8, Vs + ca * 512);
      }
    }
    __syncthreads();

    // S = Q K^T   (2 qb x 4 kvb frags)
    f32x4 s[2][4];
#pragma unroll
    for (int qb = 0; qb < 2; ++qb)
#pragma unroll
      for (int kvb = 0; kvb < 4; ++kvb) s[qb][kvb] = {0.f, 0.f, 0.f, 0.f};
#pragma unroll
    for (int kc = 0; kc < 2; ++kc) {
      bf16x8 kf[4];
#pragma unroll
      for (int kvb = 0; kvb < 4; ++kvb)
        kf[kvb] = *reinterpret_cast<const bf16x8*>(
            &Ks[(kvb * 16 + (lane & 15)) * 64 + kc * 32 + (lane >> 4) * 8]);
#pragma unroll
      for (int qb = 0; qb < 2; ++qb)
#pragma unroll
        for (int kvb = 0; kvb < 4; ++kvb)
          s[qb][kvb] = mfma16(qf[qb][kc], kf[kvb], s[qb][kvb]);
    }

    // relu -> P (bf16, per-wave LDS, D-layout scatter)
#pragma unroll
    for (int qb = 0; qb < 2; ++qb)
#pragma unroll
      for (int kvb = 0; kvb < 4; ++kvb)
#pragma unroll
        for (int r = 0; r < 4; ++r) {
          float v = s[qb][kvb][r];
          v = v > 0.f ? v : 0.f;
          Pw[(qb * 16 + (lane >> 4) * 4 + r) * 64 + kvb * 16 + (lane & 15)] = (bf16)v;
        }

    // O += P V   (A = P rows from LDS, B = V from VT tile rows)
#pragma unroll
    for (int kc = 0; kc < 2; ++kc) {
      bf16x8 pf[2], vf[4];
#pragma unroll
      for (int qb = 0; qb < 2; ++qb)
        pf[qb] = *reinterpret_cast<const bf16x8*>(
            &Pw[(qb * 16 + (lane & 15)) * 64 + kc * 32 + (lane >> 4) * 8]);
#pragma unroll
      for (int db = 0; db < 4; ++db)
        vf[db] = *reinterpret_cast<const bf16x8*>(
            &Vs[(db * 16 + (lane & 15)) * 64 + kc * 32 + (lane >> 4) * 8]);
#pragma unroll
      for (int qb = 0; qb < 2; ++qb)
#pragma unroll
        for (int db = 0; db < 4; ++db)
          o[qb][db] = mfma16(pf[qb], vf[db], o[qb][db]);
    }
  }

  const int b = bh >> 3, h = bh & 7;
#pragma unroll
  for (int qb = 0; qb < 2; ++qb)
#pragma unroll
    for (int db = 0; db < 4; ++db)
#pragma unroll
      for (int r = 0; r < 4; ++r) {
        const int n = q0 + qb * 16 + (lane >> 4) * 4 + r;
        const int dcol = db * 16 + (lane & 15);
        out[((size_t)(b * 4096 + n)) * 512 + h * 64 + dcol] = o[qb][db][r] * 0.125f;
      }
}

// ---------- LayerNorm over 512, one wave per row, bf16 out ----------
__global__ __launch_bounds__(256) void ln_kernel(const float* __restrict__ in,
                                                 const float* __restrict__ gamma,
                                                 const float* __restrict__ beta,
                                                 bf16* __restrict__ out) {
  const int lane = threadIdx.x & 63;
  const int w = threadIdx.x >> 6;
  const int row = blockIdx.x * 4 + w;
  const float* r = in + (size_t)row * 512;
  f32x4 a = *reinterpret_cast<const f32x4*>(&r[lane * 4]);
  f32x4 b = *reinterpret_cast<const f32x4*>(&r[256 + lane * 4]);
  float s = a[0] + a[1] + a[2] + a[3] + b[0] + b[1] + b[2] + b[3];
  float ss = a[0] * a[0] + a[1] * a[1] + a[2] * a[2] + a[3] * a[3] +
             b[0] * b[0] + b[1] * b[1] + b[2] * b[2] + b[3] * b[3];
#pragma unroll
  for (int off = 32; off > 0; off >>= 1) {
    s += __shfl_xor(s, off);
    ss += __shfl_xor(ss, off);
  }
  const float mean = s * (1.f / 512.f);
  const float var = ss * (1.f / 512.f) - mean * mean;
  const float rstd = rsqrtf(var + 1e-5f);
  f32x4 g0 = *reinterpret_cast<const f32x4*>(&gamma[lane * 4]);
  f32x4 g1 = *reinterpret_cast<const f32x4*>(&gamma[256 + lane * 4]);
  f32x4 e0 = *reinterpret_cast<const f32x4*>(&beta[lane * 4]);
  f32x4 e1 = *reinterpret_cast<const f32x4*>(&beta[256 + lane * 4]);
  bf16x4 o0, o1;
#pragma unroll
  for (int i = 0; i < 4; ++i) {
    o0[i] = (bf16)((a[i] - mean) * rstd * g0[i] + e0[i]);
    o1[i] = (bf16)((b[i] - mean) * rstd * g1[i] + e1[i]);
  }
  *reinterpret_cast<bf16x4*>(&out[(size_t)row * 512 + lane * 4]) = o0;
  *reinterpret_cast<bf16x4*>(&out[(size_t)row * 512 + 256 + lane * 4]) = o1;
}

extern "C" void kernel_launch(void* const* d_in, const int* in_sizes, int n_in,
                              void* d_out, int out_size, void* d_ws, size_t ws_size,
                              hipStream_t stream) {
  const float* x = (const float*)d_in[0];       // [2,4096,512]
  const float* w_qkv = (const float*)d_in[1];   // [512,1536]
  const float* ln_g = (const float*)d_in[2];    // [512]
  const float* ln_b = (const float*)d_in[3];    // [512]
  const float* w_out = (const float*)d_in[4];   // [512,512]
  const float* b_out = (const float*)d_in[5];   // [512]
  float* out = (float*)d_out;                   // [2,4096,512] f32

  char* ws = (char*)d_ws;
  size_t off = 0;
  auto alloc = [&](size_t bytes) {
    void* p = ws + off;
    off += (bytes + 255) & ~(size_t)255;
    return p;
  };
  bf16* x_bf = (bf16*)alloc((size_t)8192 * 512 * 2);
  bf16* wqkvT = (bf16*)alloc((size_t)1536 * 512 * 2);
  bf16* woutT = (bf16*)alloc((size_t)512 * 512 * 2);
  bf16* qbuf = (bf16*)alloc((size_t)16 * 4096 * 64 * 2);
  bf16* kbuf = (bf16*)alloc((size_t)16 * 4096 * 64 * 2);
  bf16* vtbuf = (bf16*)alloc((size_t)16 * 64 * 4096 * 2);
  float* attn_out = (float*)alloc((size_t)8192 * 512 * 4);
  bf16* ln_bf = (bf16*)alloc((size_t)8192 * 512 * 2);

  // 1) converts
  cvt_kernel<<<2048, 256, 0, stream>>>(x, x_bf, 8192 * 512 / 4);
  tcvt_kernel<<<1024, 256, 0, stream>>>(w_qkv, wqkvT, 512, 1536);
  tcvt_kernel<<<512, 256, 0, stream>>>(w_out, woutT, 512, 512);

  // 2) qkv = x @ w_qkv -> Q,K (row-major per head), V transposed [d][n]
  gemm_kernel<0><<<dim3(12, 64), 256, 0, stream>>>(x_bf, wqkvT, qbuf, kbuf, vtbuf,
                                                   nullptr, nullptr);

  // 3) fused relu-attention -> attn_out f32 [8192][512] (heads merged)
  attn_kernel<<<dim3(32, 16), 256, 0, stream>>>(qbuf, kbuf, vtbuf, attn_out);

  // 4) layernorm -> bf16
  ln_kernel<<<2048, 256, 0, stream>>>(attn_out, ln_g, ln_b, ln_bf);

  // 5) out = ln @ w_out + b_out -> f32
  gemm_kernel<1><<<dim3(4, 64), 256, 0, stream>>>(ln_bf, woutT, nullptr, nullptr,
                                                  nullptr, b_out, out);
}

// Round 3
// 236.790 us; speedup vs baseline: 1.2091x; 1.2091x over previous
//
#include <hip/hip_runtime.h>
#include <stdint.h>
#include <stddef.h>

typedef __bf16 bf16;
typedef bf16 bf16x4 __attribute__((ext_vector_type(4)));
typedef bf16 bf16x8 __attribute__((ext_vector_type(8)));
typedef float f32x4 __attribute__((ext_vector_type(4)));

#define DEVI static __device__ __forceinline__

// B=2, N=4096, DIM=512, HEADS=8, DHEAD=64, INNER=512

DEVI f32x4 mfma16(bf16x8 a, bf16x8 b, f32x4 c) {
  return __builtin_amdgcn_mfma_f32_16x16x32_bf16(a, b, c, 0, 0, 0);
}

DEVI void gload_lds16(const bf16* g, bf16* lds) {
  __builtin_amdgcn_global_load_lds(
      (const __attribute__((address_space(1))) unsigned int*)g,
      (__attribute__((address_space(3))) unsigned int*)lds, 16, 0, 0);
}

// LDS tiles are [R][64] bf16 (128 B rows). XOR-swizzle involution on 16B
// granules (slots of 8 elems): slot' = slot ^ (row&7).
// global_load_lds writes linearly (LDS slot = lane&7, row = base+lane>>3), so
// the SOURCE column slot is pre-swizzled: src_slot = (lane&7) ^ (row&7).
// Every read of logical slot cs fetches LDS slot cs ^ (row&7). All fragment
// rows have row&7 == lane&7, so reads are conflict-free (rule #21 / T2).
// Fragment k-slot for 16x16x32: cs = kc*4 + (lane>>4).   [round-2 bug: kc*2]

// ---------- f32 -> bf16 convert (vectorized) ----------
__global__ __launch_bounds__(256) void cvt_kernel(const float* __restrict__ in,
                                                  bf16* __restrict__ out, int n4) {
  int i = blockIdx.x * blockDim.x + threadIdx.x;
  const int stride = gridDim.x * blockDim.x;
  for (; i < n4; i += stride) {
    f32x4 v = reinterpret_cast<const f32x4*>(in)[i];
    bf16x4 o;
    o[0] = (bf16)v[0]; o[1] = (bf16)v[1]; o[2] = (bf16)v[2]; o[3] = (bf16)v[3];
    reinterpret_cast<bf16x4*>(out)[i] = o;
  }
}

// ---------- transpose-convert: in [K][N] f32 -> out [N][K] bf16 ----------
__global__ __launch_bounds__(256) void tcvt_kernel(const float* __restrict__ in,
                                                   bf16* __restrict__ out, int Kd, int Nd) {
  int i = blockIdx.x * blockDim.x + threadIdx.x;
  const int total = Kd * Nd;
  const int stride = gridDim.x * blockDim.x;
  for (; i < total; i += stride) {
    int k = i / Nd, n = i - k * Nd;
    out[(size_t)n * Kd + k] = (bf16)in[i];
  }
}

// ---------- GEMM: A[M][512] bf16 row-major, BT[N][512] bf16 row-major ----------
// 128x128 tile, BK=64, 4 waves (2x2), each wave 64x64 = 4x4 frags of 16x16x32.
// EPI 0: scatter to Q [bh][n][d], K [bh][n][d], VT [bh][d][n] as bf16 (qkv GEMM).
// EPI 1: out f32 [M][512] = acc + bias[col] (output projection).
template <int EPI>
__global__ __launch_bounds__(256) void gemm_kernel(
    const bf16* __restrict__ A, const bf16* __restrict__ BT,
    bf16* __restrict__ qo, bf16* __restrict__ ko, bf16* __restrict__ vto,
    const float* __restrict__ bias, float* __restrict__ fo) {
  constexpr int K = 512;
  __shared__ __align__(16) bf16 As[128 * 64];
  __shared__ __align__(16) bf16 Bs[128 * 64];
  const int lane = threadIdx.x & 63;
  const int w = threadIdx.x >> 6;
  const int wm = w >> 1, wn = w & 1;
  const int m0 = blockIdx.y * 128, n0 = blockIdx.x * 128;
  const int sl = lane >> 3;                    // sub-row within 8-row chunk
  const int ssc = ((lane & 7) ^ sl) * 8;       // pre-swizzled source col (elems)

  f32x4 acc[4][4];
#pragma unroll
  for (int i = 0; i < 4; ++i)
#pragma unroll
    for (int j = 0; j < 4; ++j) acc[i][j] = {0.f, 0.f, 0.f, 0.f};

  for (int kt = 0; kt < K / 64; ++kt) {
    const int k0 = kt * 64;
    __syncthreads();
#pragma unroll
    for (int c = 0; c < 4; ++c) {
      const int ca = w * 4 + c;                // 16 x 1KB calls per tile
      const int trow = ca * 8 + sl;            // tile row this lane covers
      gload_lds16(A + (size_t)(m0 + trow) * K + k0 + ssc, As + ca * 512);
      gload_lds16(BT + (size_t)(n0 + trow) * K + k0 + ssc, Bs + ca * 512);
    }
    __syncthreads();
#pragma unroll
    for (int kc = 0; kc < 2; ++kc) {
      const int cs = kc * 4 + (lane >> 4);     // k-slot 0..7 (FIXED)
      const int csw = (cs ^ (lane & 7)) * 8;   // swizzled read col (elems)
      bf16x8 af[4], bfr[4];
#pragma unroll
      for (int mi = 0; mi < 4; ++mi)
        af[mi] = *reinterpret_cast<const bf16x8*>(
            &As[(wm * 64 + mi * 16 + (lane & 15)) * 64 + csw]);
#pragma unroll
      for (int ni = 0; ni < 4; ++ni)
        bfr[ni] = *reinterpret_cast<const bf16x8*>(
            &Bs[(wn * 64 + ni * 16 + (lane & 15)) * 64 + csw]);
#pragma unroll
      for (int mi = 0; mi < 4; ++mi)
#pragma unroll
        for (int ni = 0; ni < 4; ++ni)
          acc[mi][ni] = mfma16(af[mi], bfr[ni], acc[mi][ni]);
    }
  }

#pragma unroll
  for (int mi = 0; mi < 4; ++mi) {
#pragma unroll
    for (int ni = 0; ni < 4; ++ni) {
#pragma unroll
      for (int r = 0; r < 4; ++r) {
        const int m = m0 + wm * 64 + mi * 16 + (lane >> 4) * 4 + r;
        const int col = n0 + wn * 64 + ni * 16 + (lane & 15);
        const float v = acc[mi][ni][r];
        if (EPI == 0) {
          const int b = m >> 12, n = m & 4095;
          const int sec = col >> 9, jj = col & 511, h = jj >> 6, d = jj & 63;
          const int bh = b * 8 + h;
          const bf16 hv = (bf16)v;
          if (sec == 0)
            qo[((size_t)bh * 4096 + n) * 64 + d] = hv;
          else if (sec == 1)
            ko[((size_t)bh * 4096 + n) * 64 + d] = hv;
          else
            vto[((size_t)bh * 64 + d) * 4096 + n] = hv;
        } else {
          fo[(size_t)m * 512 + col] = v + bias[col];
        }
      }
    }
  }
}

// ---------- fused relu-attention ----------
// grid (32 q-tiles, 16 bh, 2 kv-halves). 4 waves/block; wave owns 32 q rows.
// Per kv-chunk of 64: stage K [64][64] and VT [64][64] in LDS (swizzled),
// QK^T (MFMA), relu -> P (per-wave LDS, swizzled), PV (MFMA).
// scale deferred to the final O write (relu(s*c) = c*relu(s), c>0).
// KV-split: relu-attn is a pure sum, so each z-half writes a partial f32
// buffer; LN adds them.
__global__ __launch_bounds__(256) void attn_kernel(
    const bf16* __restrict__ Q, const bf16* __restrict__ Kg,
    const bf16* __restrict__ VT, float* __restrict__ out0,
    float* __restrict__ out1) {
  __shared__ __align__(16) bf16 Ks[64 * 64];       // [kv][d] swizzled
  __shared__ __align__(16) bf16 Vs[64 * 64];       // [d][kv] swizzled
  __shared__ __align__(16) bf16 Ps[4][32 * 64];    // per-wave [q][kv] swizzled
  const int lane = threadIdx.x & 63;
  const int w = threadIdx.x >> 6;
  const int bh = blockIdx.y;
  const int q0 = blockIdx.x * 128 + w * 32;
  const int kvbase = blockIdx.z * 2048;
  const bf16* Qh = Q + (size_t)bh * 4096 * 64;
  const bf16* Kh = Kg + (size_t)bh * 4096 * 64;
  const bf16* Vh = VT + (size_t)bh * 64 * 4096;
  float* outp = blockIdx.z ? out1 : out0;

  bf16x8 qf[2][2];
#pragma unroll
  for (int qb = 0; qb < 2; ++qb)
#pragma unroll
    for (int kc = 0; kc < 2; ++kc)
      qf[qb][kc] = *reinterpret_cast<const bf16x8*>(
          &Qh[(size_t)(q0 + qb * 16 + (lane & 15)) * 64 + kc * 32 + (lane >> 4) * 8]);

  f32x4 o[2][4];
#pragma unroll
  for (int qb = 0; qb < 2; ++qb)
#pragma unroll
    for (int db = 0; db < 4; ++db) o[qb][db] = {0.f, 0.f, 0.f, 0.f};

  bf16* Pw = Ps[w];
  const int sl = lane >> 3;
  const int ssc = ((lane & 7) ^ sl) * 8;           // pre-swizzled source col

  for (int kv0 = kvbase; kv0 < kvbase + 2048; kv0 += 64) {
    __syncthreads();
    if (w < 2) {  // waves 0-1: K tile rows kv0..kv0+63
#pragma unroll
      for (int c = 0; c < 4; ++c) {
        const int ca = w * 4 + c;
        const int r = ca * 8 + sl;
        gload_lds16(Kh + (size_t)(kv0 + r) * 64 + ssc, Ks + ca * 512);
      }
    } else {  // waves 2-3: VT tile rows d=0..63 (row stride 4096 in global)
#pragma unroll
      for (int c = 0; c < 4; ++c) {
        const int ca = (w - 2) * 4 + c;
        const int d = ca * 8 + sl;
        gload_lds16(Vh + (size_t)d * 4096 + kv0 + ssc, Vs + ca * 512);
      }
    }
    __syncthreads();

    // S = Q K^T   (2 qb x 4 kvb frags)
    f32x4 s[2][4];
#pragma unroll
    for (int qb = 0; qb < 2; ++qb)
#pragma unroll
      for (int kvb = 0; kvb < 4; ++kvb) s[qb][kvb] = {0.f, 0.f, 0.f, 0.f};
#pragma unroll
    for (int kc = 0; kc < 2; ++kc) {
      const int csw = ((kc * 4 + (lane >> 4)) ^ (lane & 7)) * 8;  // FIXED
      bf16x8 kf[4];
#pragma unroll
      for (int kvb = 0; kvb < 4; ++kvb)
        kf[kvb] = *reinterpret_cast<const bf16x8*>(
            &Ks[(kvb * 16 + (lane & 15)) * 64 + csw]);
#pragma unroll
      for (int qb = 0; qb < 2; ++qb)
#pragma unroll
        for (int kvb = 0; kvb < 4; ++kvb)
          s[qb][kvb] = mfma16(qf[qb][kc], kf[kvb], s[qb][kvb]);
    }

    // relu -> P (bf16, per-wave LDS, swizzled scatter)
#pragma unroll
    for (int qb = 0; qb < 2; ++qb)
#pragma unroll
      for (int kvb = 0; kvb < 4; ++kvb)
#pragma unroll
        for (int r = 0; r < 4; ++r) {
          float v = s[qb][kvb][r];
          v = v > 0.f ? v : 0.f;
          const int prow = qb * 16 + (lane >> 4) * 4 + r;
          const int pcol = (kvb * 16 + (lane & 15)) ^ ((prow & 7) << 3);
          Pw[prow * 64 + pcol] = (bf16)v;
        }

    // O += P V   (A = P rows from LDS, B = V from VT tile rows)
#pragma unroll
    for (int kc = 0; kc < 2; ++kc) {
      const int csw = ((kc * 4 + (lane >> 4)) ^ (lane & 7)) * 8;  // FIXED
      bf16x8 pf[2], vf[4];
#pragma unroll
      for (int qb = 0; qb < 2; ++qb)
        pf[qb] = *reinterpret_cast<const bf16x8*>(
            &Pw[(qb * 16 + (lane & 15)) * 64 + csw]);
#pragma unroll
      for (int db = 0; db < 4; ++db)
        vf[db] = *reinterpret_cast<const bf16x8*>(
            &Vs[(db * 16 + (lane & 15)) * 64 + csw]);
#pragma unroll
      for (int qb = 0; qb < 2; ++qb)
#pragma unroll
        for (int db = 0; db < 4; ++db)
          o[qb][db] = mfma16(pf[qb], vf[db], o[qb][db]);
    }
  }

  const int b = bh >> 3, h = bh & 7;
#pragma unroll
  for (int qb = 0; qb < 2; ++qb)
#pragma unroll
    for (int db = 0; db < 4; ++db)
#pragma unroll
      for (int r = 0; r < 4; ++r) {
        const int n = q0 + qb * 16 + (lane >> 4) * 4 + r;
        const int dcol = db * 16 + (lane & 15);
        outp[((size_t)(b * 4096 + n)) * 512 + h * 64 + dcol] = o[qb][db][r] * 0.125f;
      }
}

// ---------- LayerNorm over 512 of (in0+in1), one wave per row, bf16 out ----------
__global__ __launch_bounds__(256) void ln_kernel(const float* __restrict__ in0,
                                                 const float* __restrict__ in1,
                                                 const float* __restrict__ gamma,
                                                 const float* __restrict__ beta,
                                                 bf16* __restrict__ out) {
  const int lane = threadIdx.x & 63;
  const int w = threadIdx.x >> 6;
  const int row = blockIdx.x * 4 + w;
  const float* r0 = in0 + (size_t)row * 512;
  const float* r1 = in1 + (size_t)row * 512;
  f32x4 a = *reinterpret_cast<const f32x4*>(&r0[lane * 4]);
  f32x4 b = *reinterpret_cast<const f32x4*>(&r0[256 + lane * 4]);
  f32x4 a1 = *reinterpret_cast<const f32x4*>(&r1[lane * 4]);
  f32x4 b1 = *reinterpret_cast<const f32x4*>(&r1[256 + lane * 4]);
#pragma unroll
  for (int i = 0; i < 4; ++i) { a[i] += a1[i]; b[i] += b1[i]; }
  float s = a[0] + a[1] + a[2] + a[3] + b[0] + b[1] + b[2] + b[3];
  float ss = a[0] * a[0] + a[1] * a[1] + a[2] * a[2] + a[3] * a[3] +
             b[0] * b[0] + b[1] * b[1] + b[2] * b[2] + b[3] * b[3];
#pragma unroll
  for (int off = 32; off > 0; off >>= 1) {
    s += __shfl_xor(s, off);
    ss += __shfl_xor(ss, off);
  }
  const float mean = s * (1.f / 512.f);
  const float var = ss * (1.f / 512.f) - mean * mean;
  const float rstd = rsqrtf(var + 1e-5f);
  f32x4 g0 = *reinterpret_cast<const f32x4*>(&gamma[lane * 4]);
  f32x4 g1 = *reinterpret_cast<const f32x4*>(&gamma[256 + lane * 4]);
  f32x4 e0 = *reinterpret_cast<const f32x4*>(&beta[lane * 4]);
  f32x4 e1 = *reinterpret_cast<const f32x4*>(&beta[256 + lane * 4]);
  bf16x4 o0, o1;
#pragma unroll
  for (int i = 0; i < 4; ++i) {
    o0[i] = (bf16)((a[i] - mean) * rstd * g0[i] + e0[i]);
    o1[i] = (bf16)((b[i] - mean) * rstd * g1[i] + e1[i]);
  }
  *reinterpret_cast<bf16x4*>(&out[(size_t)row * 512 + lane * 4]) = o0;
  *reinterpret_cast<bf16x4*>(&out[(size_t)row * 512 + 256 + lane * 4]) = o1;
}

extern "C" void kernel_launch(void* const* d_in, const int* in_sizes, int n_in,
                              void* d_out, int out_size, void* d_ws, size_t ws_size,
                              hipStream_t stream) {
  const float* x = (const float*)d_in[0];       // [2,4096,512]
  const float* w_qkv = (const float*)d_in[1];   // [512,1536]
  const float* ln_g = (const float*)d_in[2];    // [512]
  const float* ln_b = (const float*)d_in[3];    // [512]
  const float* w_out = (const float*)d_in[4];   // [512,512]
  const float* b_out = (const float*)d_in[5];   // [512]
  float* out = (float*)d_out;                   // [2,4096,512] f32

  char* ws = (char*)d_ws;
  size_t off = 0;
  auto alloc = [&](size_t bytes) {
    void* p = ws + off;
    off += (bytes + 255) & ~(size_t)255;
    return p;
  };
  bf16* x_bf = (bf16*)alloc((size_t)8192 * 512 * 2);
  bf16* wqkvT = (bf16*)alloc((size_t)1536 * 512 * 2);
  bf16* woutT = (bf16*)alloc((size_t)512 * 512 * 2);
  bf16* qbuf = (bf16*)alloc((size_t)16 * 4096 * 64 * 2);
  bf16* kbuf = (bf16*)alloc((size_t)16 * 4096 * 64 * 2);
  bf16* vtbuf = (bf16*)alloc((size_t)16 * 64 * 4096 * 2);
  float* attn_out0 = (float*)alloc((size_t)8192 * 512 * 4);
  float* attn_out1 = (float*)alloc((size_t)8192 * 512 * 4);
  bf16* ln_bf = (bf16*)alloc((size_t)8192 * 512 * 2);

  // 1) converts
  cvt_kernel<<<2048, 256, 0, stream>>>(x, x_bf, 8192 * 512 / 4);
  tcvt_kernel<<<1024, 256, 0, stream>>>(w_qkv, wqkvT, 512, 1536);
  tcvt_kernel<<<512, 256, 0, stream>>>(w_out, woutT, 512, 512);

  // 2) qkv = x @ w_qkv -> Q,K (row-major per head), V transposed [d][n]
  gemm_kernel<0><<<dim3(12, 64), 256, 0, stream>>>(x_bf, wqkvT, qbuf, kbuf, vtbuf,
                                                   nullptr, nullptr);

  // 3) fused relu-attention -> two partial f32 buffers (kv-split halves)
  attn_kernel<<<dim3(32, 16, 2), 256, 0, stream>>>(qbuf, kbuf, vtbuf,
                                                   attn_out0, attn_out1);

  // 4) layernorm(sum of halves) -> bf16
  ln_kernel<<<2048, 256, 0, stream>>>(attn_out0, attn_out1, ln_g, ln_b, ln_bf);

  // 5) out = ln @ w_out + b_out -> f32
  gemm_kernel<1><<<dim3(4, 64), 256, 0, stream>>>(ln_bf, woutT, nullptr, nullptr,
                                                  nullptr, b_out, out);
}

// Round 4
// 224.161 us; speedup vs baseline: 1.2772x; 1.0563x over previous
//
#include <hip/hip_runtime.h>
#include <stdint.h>
#include <stddef.h>

typedef __bf16 bf16;
typedef bf16 bf16x4 __attribute__((ext_vector_type(4)));
typedef bf16 bf16x8 __attribute__((ext_vector_type(8)));
typedef float f32x4 __attribute__((ext_vector_type(4)));

#define DEVI static __device__ __forceinline__

// B=2, N=4096, DIM=512, HEADS=8, DHEAD=64, INNER=512

DEVI f32x4 mfma16(bf16x8 a, bf16x8 b, f32x4 c) {
  return __builtin_amdgcn_mfma_f32_16x16x32_bf16(a, b, c, 0, 0, 0);
}

DEVI void gload_lds16(const bf16* g, bf16* lds) {
  __builtin_amdgcn_global_load_lds(
      (const __attribute__((address_space(1))) unsigned int*)g,
      (__attribute__((address_space(3))) unsigned int*)lds, 16, 0, 0);
}

// LDS tiles are [R][64] bf16 (128 B rows). XOR-swizzle involution on 16B
// granules (slots of 8 elems): slot' = slot ^ (row&7).
// global_load_lds writes linearly (LDS slot = lane&7, row = base+lane>>3), so
// the SOURCE column slot is pre-swizzled: src_slot = (lane&7) ^ (row&7).
// Every read of logical slot cs fetches LDS slot cs ^ (row&7). All fragment
// rows have row&7 == lane&7, so reads are conflict-free (rule #21 / T2).
// Fragment k-slot for 16x16x32: cs = kc*4 + (lane>>4).

// ---------- f32 -> bf16 convert (vectorized) ----------
__global__ __launch_bounds__(256) void cvt_kernel(const float* __restrict__ in,
                                                  bf16* __restrict__ out, int n4) {
  int i = blockIdx.x * blockDim.x + threadIdx.x;
  const int stride = gridDim.x * blockDim.x;
  for (; i < n4; i += stride) {
    f32x4 v = reinterpret_cast<const f32x4*>(in)[i];
    bf16x4 o;
    o[0] = (bf16)v[0]; o[1] = (bf16)v[1]; o[2] = (bf16)v[2]; o[3] = (bf16)v[3];
    reinterpret_cast<bf16x4*>(out)[i] = o;
  }
}

// ---------- transpose-convert: in [K][N] f32 -> out [N][K] bf16 ----------
__global__ __launch_bounds__(256) void tcvt_kernel(const float* __restrict__ in,
                                                   bf16* __restrict__ out, int Kd, int Nd) {
  int i = blockIdx.x * blockDim.x + threadIdx.x;
  const int total = Kd * Nd;
  const int stride = gridDim.x * blockDim.x;
  for (; i < total; i += stride) {
    int k = i / Nd, n = i - k * Nd;
    out[(size_t)n * Kd + k] = (bf16)in[i];
  }
}

// ---------- GEMM: A[M][512] bf16 row-major, BT[N][512] bf16 row-major ----------
// 128x128 tile, BK=64, 4 waves (2x2), each wave 64x64 = 4x4 frags of 16x16x32.
// EPI 0: scatter to Q [bh][n][d], K [bh][n][d], VT [bh][d][n] as bf16 (qkv GEMM).
// EPI 1: out f32 [M][512] = acc + bias[col] (output projection).
template <int EPI>
__global__ __launch_bounds__(256) void gemm_kernel(
    const bf16* __restrict__ A, const bf16* __restrict__ BT,
    bf16* __restrict__ qo, bf16* __restrict__ ko, bf16* __restrict__ vto,
    const float* __restrict__ bias, float* __restrict__ fo) {
  constexpr int K = 512;
  __shared__ __align__(16) bf16 As[128 * 64];
  __shared__ __align__(16) bf16 Bs[128 * 64];
  const int lane = threadIdx.x & 63;
  const int w = threadIdx.x >> 6;
  const int wm = w >> 1, wn = w & 1;
  const int m0 = blockIdx.y * 128, n0 = blockIdx.x * 128;
  const int sl = lane >> 3;                    // sub-row within 8-row chunk
  const int ssc = ((lane & 7) ^ sl) * 8;       // pre-swizzled source col (elems)

  f32x4 acc[4][4];
#pragma unroll
  for (int i = 0; i < 4; ++i)
#pragma unroll
    for (int j = 0; j < 4; ++j) acc[i][j] = {0.f, 0.f, 0.f, 0.f};

  for (int kt = 0; kt < K / 64; ++kt) {
    const int k0 = kt * 64;
    __syncthreads();
#pragma unroll
    for (int c = 0; c < 4; ++c) {
      const int ca = w * 4 + c;                // 16 x 1KB calls per tile
      const int trow = ca * 8 + sl;            // tile row this lane covers
      gload_lds16(A + (size_t)(m0 + trow) * K + k0 + ssc, As + ca * 512);
      gload_lds16(BT + (size_t)(n0 + trow) * K + k0 + ssc, Bs + ca * 512);
    }
    __syncthreads();
#pragma unroll
    for (int kc = 0; kc < 2; ++kc) {
      const int cs = kc * 4 + (lane >> 4);     // k-slot 0..7
      const int csw = (cs ^ (lane & 7)) * 8;   // swizzled read col (elems)
      bf16x8 af[4], bfr[4];
#pragma unroll
      for (int mi = 0; mi < 4; ++mi)
        af[mi] = *reinterpret_cast<const bf16x8*>(
            &As[(wm * 64 + mi * 16 + (lane & 15)) * 64 + csw]);
#pragma unroll
      for (int ni = 0; ni < 4; ++ni)
        bfr[ni] = *reinterpret_cast<const bf16x8*>(
            &Bs[(wn * 64 + ni * 16 + (lane & 15)) * 64 + csw]);
#pragma unroll
      for (int mi = 0; mi < 4; ++mi)
#pragma unroll
        for (int ni = 0; ni < 4; ++ni)
          acc[mi][ni] = mfma16(af[mi], bfr[ni], acc[mi][ni]);
    }
  }

#pragma unroll
  for (int mi = 0; mi < 4; ++mi) {
#pragma unroll
    for (int ni = 0; ni < 4; ++ni) {
#pragma unroll
      for (int r = 0; r < 4; ++r) {
        const int m = m0 + wm * 64 + mi * 16 + (lane >> 4) * 4 + r;
        const int col = n0 + wn * 64 + ni * 16 + (lane & 15);
        const float v = acc[mi][ni][r];
        if (EPI == 0) {
          const int b = m >> 12, n = m & 4095;
          const int sec = col >> 9, jj = col & 511, h = jj >> 6, d = jj & 63;
          const int bh = b * 8 + h;
          const bf16 hv = (bf16)v;
          if (sec == 0)
            qo[((size_t)bh * 4096 + n) * 64 + d] = hv;
          else if (sec == 1)
            ko[((size_t)bh * 4096 + n) * 64 + d] = hv;
          else
            vto[((size_t)bh * 64 + d) * 4096 + n] = hv;
        } else {
          fo[(size_t)m * 512 + col] = v + bias[col];
        }
      }
    }
  }
}

// ---------- fused relu-attention (round 4: prefetch dbuf + swapped QK^T) ----------
// grid (32 q-tiles, 16 bh, 2 kv-halves). 4 waves/block; wave owns 32 q rows.
// 2-phase pipeline (T3 minimum recipe): STAGE(next buf) -> compute(cur buf)
// -> vmcnt(0) -> s_barrier. Raw barriers (no __syncthreads drain); prefetch
// latency hides under QK^T/P/PV compute.
// QK^T computed SWAPPED: s = mfma(K,Q) = S^T, so regs r0..3 hold 4 consecutive
// kv for fixed q=lane&15 -> relu+pack -> 8x ds_write_b64 (was 32x b16).
// scale deferred to the final O write (relu(s*c) = c*relu(s), c>0).
__global__ __launch_bounds__(256) void attn_kernel(
    const bf16* __restrict__ Q, const bf16* __restrict__ Kg,
    const bf16* __restrict__ VT, float* __restrict__ out0,
    float* __restrict__ out1) {
  __shared__ __align__(16) bf16 Ks[2 * 64 * 64];   // dbuf [kv][d] swizzled
  __shared__ __align__(16) bf16 Vs[2 * 64 * 64];   // dbuf [d][kv] swizzled
  __shared__ __align__(16) bf16 Ps[4][32 * 64];    // per-wave [q][kv] swizzled
  const int lane = threadIdx.x & 63;
  const int w = threadIdx.x >> 6;
  const int hi = lane >> 4;
  const int bh = blockIdx.y;
  const int q0 = blockIdx.x * 128 + w * 32;
  const int kvbase = blockIdx.z * 2048;
  const bf16* Qh = Q + (size_t)bh * 4096 * 64;
  const bf16* Kh = Kg + (size_t)bh * 4096 * 64;
  const bf16* Vh = VT + (size_t)bh * 64 * 4096;
  float* outp = blockIdx.z ? out1 : out0;

  const int sl = lane >> 3;
  const int ssc = ((lane & 7) ^ sl) * 8;           // pre-swizzled source col

  // stage one KV chunk (64 kv) into buffer bi
  auto stage = [&](int bi, int kv0) {
    bf16* KsB = Ks + bi * 4096;
    bf16* VsB = Vs + bi * 4096;
    if (w < 2) {  // waves 0-1: K tile rows kv0..kv0+63
#pragma unroll
      for (int c = 0; c < 4; ++c) {
        const int ca = w * 4 + c;
        const int r = ca * 8 + sl;
        gload_lds16(Kh + (size_t)(kv0 + r) * 64 + ssc, KsB + ca * 512);
      }
    } else {  // waves 2-3: VT tile rows d=0..63 (row stride 4096 in global)
#pragma unroll
      for (int c = 0; c < 4; ++c) {
        const int ca = (w - 2) * 4 + c;
        const int d = ca * 8 + sl;
        gload_lds16(Vh + (size_t)d * 4096 + kv0 + ssc, VsB + ca * 512);
      }
    }
  };

  bf16x8 qf[2][2];
#pragma unroll
  for (int qb = 0; qb < 2; ++qb)
#pragma unroll
    for (int kc = 0; kc < 2; ++kc)
      qf[qb][kc] = *reinterpret_cast<const bf16x8*>(
          &Qh[(size_t)(q0 + qb * 16 + (lane & 15)) * 64 + kc * 32 + hi * 8]);

  f32x4 o[2][4];
#pragma unroll
  for (int qb = 0; qb < 2; ++qb)
#pragma unroll
    for (int db = 0; db < 4; ++db) o[qb][db] = {0.f, 0.f, 0.f, 0.f};

  bf16* Pw = Ps[w];

  // prologue: stage tile 0, wait, barrier
  stage(0, kvbase);
  asm volatile("s_waitcnt vmcnt(0)" ::: "memory");
  __builtin_amdgcn_s_barrier();

  for (int it = 0; it < 32; ++it) {
    const int kv0 = kvbase + it * 64;
    const int cur = it & 1;
    const bf16* KsC = Ks + cur * 4096;
    const bf16* VsC = Vs + cur * 4096;
    if (it < 31) stage(cur ^ 1, kv0 + 64);   // prefetch next tile

    // S^T = K Q^T  (swapped: D rows = kv, cols = q)
    f32x4 s[2][4];
#pragma unroll
    for (int qb = 0; qb < 2; ++qb)
#pragma unroll
      for (int kvb = 0; kvb < 4; ++kvb) s[qb][kvb] = {0.f, 0.f, 0.f, 0.f};
#pragma unroll
    for (int kc = 0; kc < 2; ++kc) {
      const int csw = ((kc * 4 + hi) ^ (lane & 7)) * 8;
      bf16x8 kf[4];
#pragma unroll
      for (int kvb = 0; kvb < 4; ++kvb)
        kf[kvb] = *reinterpret_cast<const bf16x8*>(
            &KsC[(kvb * 16 + (lane & 15)) * 64 + csw]);
      __builtin_amdgcn_s_setprio(1);
#pragma unroll
      for (int qb = 0; qb < 2; ++qb)
#pragma unroll
        for (int kvb = 0; kvb < 4; ++kvb)
          s[qb][kvb] = mfma16(kf[kvb], qf[qb][kc], s[qb][kvb]);
      __builtin_amdgcn_s_setprio(0);
    }

    // relu -> P: lane holds q=lane&15 (col), kv=kvb*16+hi*4+r (rows) ->
    // pack 4 consecutive kv into bf16x4, one ds_write_b64 per (qb,kvb).
#pragma unroll
    for (int qb = 0; qb < 2; ++qb) {
      const int prow = qb * 16 + (lane & 15);
      const int swz = (prow & 7) << 3;
#pragma unroll
      for (int kvb = 0; kvb < 4; ++kvb) {
        bf16x4 pq;
#pragma unroll
        for (int r = 0; r < 4; ++r) {
          float v = s[qb][kvb][r];
          pq[r] = (bf16)(v > 0.f ? v : 0.f);
        }
        const int ebase = (kvb * 16 + hi * 4) ^ swz;   // 4-elem aligned
        *reinterpret_cast<bf16x4*>(&Pw[prow * 64 + ebase]) = pq;
      }
    }

    // O += P V   (A = P rows from LDS, B = V from VT tile rows)
#pragma unroll
    for (int kc = 0; kc < 2; ++kc) {
      const int csw = ((kc * 4 + hi) ^ (lane & 7)) * 8;
      bf16x8 pf[2], vf[4];
#pragma unroll
      for (int qb = 0; qb < 2; ++qb)
        pf[qb] = *reinterpret_cast<const bf16x8*>(
            &Pw[(qb * 16 + (lane & 15)) * 64 + csw]);
#pragma unroll
      for (int db = 0; db < 4; ++db)
        vf[db] = *reinterpret_cast<const bf16x8*>(
            &VsC[(db * 16 + (lane & 15)) * 64 + csw]);
      __builtin_amdgcn_s_setprio(1);
#pragma unroll
      for (int qb = 0; qb < 2; ++qb)
#pragma unroll
        for (int db = 0; db < 4; ++db)
          o[qb][db] = mfma16(pf[qb], vf[db], o[qb][db]);
      __builtin_amdgcn_s_setprio(0);
    }

    // drain this iter's prefetch (latency already covered by compute), flip
    asm volatile("s_waitcnt vmcnt(0)" ::: "memory");
    __builtin_amdgcn_s_barrier();
  }

  const int b = bh >> 3, h = bh & 7;
#pragma unroll
  for (int qb = 0; qb < 2; ++qb)
#pragma unroll
    for (int db = 0; db < 4; ++db)
#pragma unroll
      for (int r = 0; r < 4; ++r) {
        const int n = q0 + qb * 16 + hi * 4 + r;
        const int dcol = db * 16 + (lane & 15);
        outp[((size_t)(b * 4096 + n)) * 512 + h * 64 + dcol] = o[qb][db][r] * 0.125f;
      }
}

// ---------- LayerNorm over 512 of (in0+in1), one wave per row, bf16 out ----------
__global__ __launch_bounds__(256) void ln_kernel(const float* __restrict__ in0,
                                                 const float* __restrict__ in1,
                                                 const float* __restrict__ gamma,
                                                 const float* __restrict__ beta,
                                                 bf16* __restrict__ out) {
  const int lane = threadIdx.x & 63;
  const int w = threadIdx.x >> 6;
  const int row = blockIdx.x * 4 + w;
  const float* r0 = in0 + (size_t)row * 512;
  const float* r1 = in1 + (size_t)row * 512;
  f32x4 a = *reinterpret_cast<const f32x4*>(&r0[lane * 4]);
  f32x4 b = *reinterpret_cast<const f32x4*>(&r0[256 + lane * 4]);
  f32x4 a1 = *reinterpret_cast<const f32x4*>(&r1[lane * 4]);
  f32x4 b1 = *reinterpret_cast<const f32x4*>(&r1[256 + lane * 4]);
#pragma unroll
  for (int i = 0; i < 4; ++i) { a[i] += a1[i]; b[i] += b1[i]; }
  float s = a[0] + a[1] + a[2] + a[3] + b[0] + b[1] + b[2] + b[3];
  float ss = a[0] * a[0] + a[1] * a[1] + a[2] * a[2] + a[3] * a[3] +
             b[0] * b[0] + b[1] * b[1] + b[2] * b[2] + b[3] * b[3];
#pragma unroll
  for (int off = 32; off > 0; off >>= 1) {
    s += __shfl_xor(s, off);
    ss += __shfl_xor(ss, off);
  }
  const float mean = s * (1.f / 512.f);
  const float var = ss * (1.f / 512.f) - mean * mean;
  const float rstd = rsqrtf(var + 1e-5f);
  f32x4 g0 = *reinterpret_cast<const f32x4*>(&gamma[lane * 4]);
  f32x4 g1 = *reinterpret_cast<const f32x4*>(&gamma[256 + lane * 4]);
  f32x4 e0 = *reinterpret_cast<const f32x4*>(&beta[lane * 4]);
  f32x4 e1 = *reinterpret_cast<const f32x4*>(&beta[256 + lane * 4]);
  bf16x4 o0, o1;
#pragma unroll
  for (int i = 0; i < 4; ++i) {
    o0[i] = (bf16)((a[i] - mean) * rstd * g0[i] + e0[i]);
    o1[i] = (bf16)((b[i] - mean) * rstd * g1[i] + e1[i]);
  }
  *reinterpret_cast<bf16x4*>(&out[(size_t)row * 512 + lane * 4]) = o0;
  *reinterpret_cast<bf16x4*>(&out[(size_t)row * 512 + 256 + lane * 4]) = o1;
}

extern "C" void kernel_launch(void* const* d_in, const int* in_sizes, int n_in,
                              void* d_out, int out_size, void* d_ws, size_t ws_size,
                              hipStream_t stream) {
  const float* x = (const float*)d_in[0];       // [2,4096,512]
  const float* w_qkv = (const float*)d_in[1];   // [512,1536]
  const float* ln_g = (const float*)d_in[2];    // [512]
  const float* ln_b = (const float*)d_in[3];    // [512]
  const float* w_out = (const float*)d_in[4];   // [512,512]
  const float* b_out = (const float*)d_in[5];   // [512]
  float* out = (float*)d_out;                   // [2,4096,512] f32

  char* ws = (char*)d_ws;
  size_t off = 0;
  auto alloc = [&](size_t bytes) {
    void* p = ws + off;
    off += (bytes + 255) & ~(size_t)255;
    return p;
  };
  bf16* x_bf = (bf16*)alloc((size_t)8192 * 512 * 2);
  bf16* wqkvT = (bf16*)alloc((size_t)1536 * 512 * 2);
  bf16* woutT = (bf16*)alloc((size_t)512 * 512 * 2);
  bf16* qbuf = (bf16*)alloc((size_t)16 * 4096 * 64 * 2);
  bf16* kbuf = (bf16*)alloc((size_t)16 * 4096 * 64 * 2);
  bf16* vtbuf = (bf16*)alloc((size_t)16 * 64 * 4096 * 2);
  float* attn_out0 = (float*)alloc((size_t)8192 * 512 * 4);
  float* attn_out1 = (float*)alloc((size_t)8192 * 512 * 4);
  bf16* ln_bf = (bf16*)alloc((size_t)8192 * 512 * 2);

  // 1) converts
  cvt_kernel<<<2048, 256, 0, stream>>>(x, x_bf, 8192 * 512 / 4);
  tcvt_kernel<<<1024, 256, 0, stream>>>(w_qkv, wqkvT, 512, 1536);
  tcvt_kernel<<<512, 256, 0, stream>>>(w_out, woutT, 512, 512);

  // 2) qkv = x @ w_qkv -> Q,K (row-major per head), V transposed [d][n]
  gemm_kernel<0><<<dim3(12, 64), 256, 0, stream>>>(x_bf, wqkvT, qbuf, kbuf, vtbuf,
                                                   nullptr, nullptr);

  // 3) fused relu-attention -> two partial f32 buffers (kv-split halves)
  attn_kernel<<<dim3(32, 16, 2), 256, 0, stream>>>(qbuf, kbuf, vtbuf,
                                                   attn_out0, attn_out1);

  // 4) layernorm(sum of halves) -> bf16
  ln_kernel<<<2048, 256, 0, stream>>>(attn_out0, attn_out1, ln_g, ln_b, ln_bf);

  // 5) out = ln @ w_out + b_out -> f32
  gemm_kernel<1><<<dim3(4, 64), 256, 0, stream>>>(ln_bf, woutT, nullptr, nullptr,
                                                  nullptr, b_out, out);
}

// Round 5
// 191.625 us; speedup vs baseline: 1.4941x; 1.1698x over previous
//
#include <hip/hip_runtime.h>
#include <stdint.h>
#include <stddef.h>

typedef __bf16 bf16;
typedef bf16 bf16x4 __attribute__((ext_vector_type(4)));
typedef bf16 bf16x8 __attribute__((ext_vector_type(8)));
typedef float f32x4 __attribute__((ext_vector_type(4)));

#define DEVI static __device__ __forceinline__

// B=2, N=4096, DIM=512, HEADS=8, DHEAD=64, INNER=512

DEVI f32x4 mfma16(bf16x8 a, bf16x8 b, f32x4 c) {
  return __builtin_amdgcn_mfma_f32_16x16x32_bf16(a, b, c, 0, 0, 0);
}

DEVI void gload_lds16(const bf16* g, bf16* lds) {
  __builtin_amdgcn_global_load_lds(
      (const __attribute__((address_space(1))) unsigned int*)g,
      (__attribute__((address_space(3))) unsigned int*)lds, 16, 0, 0);
}

// kv bit-permutation for in-register P (see round-5 notes):
// sigma(32kc+16u+4hi+r) = 32kc+8hi+4u+r.  S^T computed against K rows staged
// in sigma order makes the S^T D-fragment coincide with the PV A-fragment.
DEVI int sigma64(int r) { return (r & 0x23) | ((r & 0xC) << 1) | ((r & 0x10) >> 2); }

// LDS tiles are [R][64] bf16 (128 B rows). XOR-swizzle involution on 16B
// granules (slots of 8 elems): slot' = slot ^ (row&7).
// global_load_lds writes linearly (LDS slot = lane&7, row = base+lane>>3), so
// the SOURCE column slot is pre-swizzled: src_slot = (lane&7) ^ (row&7).
// Every read of logical slot cs fetches LDS slot cs ^ (row&7). All fragment
// rows have row&7 == lane&7, so reads are conflict-free (rule #21 / T2).
// Fragment k-slot for 16x16x32: cs = kc*4 + (lane>>4).

// ---------- f32 -> bf16 convert (vectorized) ----------
__global__ __launch_bounds__(256) void cvt_kernel(const float* __restrict__ in,
                                                  bf16* __restrict__ out, int n4) {
  int i = blockIdx.x * blockDim.x + threadIdx.x;
  const int stride = gridDim.x * blockDim.x;
  for (; i < n4; i += stride) {
    f32x4 v = reinterpret_cast<const f32x4*>(in)[i];
    bf16x4 o;
    o[0] = (bf16)v[0]; o[1] = (bf16)v[1]; o[2] = (bf16)v[2]; o[3] = (bf16)v[3];
    reinterpret_cast<bf16x4*>(out)[i] = o;
  }
}

// ---------- transpose-convert: in [K][N] f32 -> out [N][K] bf16 ----------
__global__ __launch_bounds__(256) void tcvt_kernel(const float* __restrict__ in,
                                                   bf16* __restrict__ out, int Kd, int Nd) {
  int i = blockIdx.x * blockDim.x + threadIdx.x;
  const int total = Kd * Nd;
  const int stride = gridDim.x * blockDim.x;
  for (; i < total; i += stride) {
    int k = i / Nd, n = i - k * Nd;
    out[(size_t)n * Kd + k] = (bf16)in[i];
  }
}

// ---------- GEMM: A[M][512] bf16 row-major, BT[N][512] bf16 row-major ----------
// 128x128 tile, BK=64, 4 waves (2x2), each wave 64x64 = 4x4 frags of 16x16x32.
// EPI 0: Q,K scatter per-head; V blocks (n0>=1024) transpose via LDS and write
//        vto [bh][d][n] with 128B-contiguous rows.
// EPI 1: out f32 [M][512] = acc + bias[col] (output projection).
template <int EPI>
__global__ __launch_bounds__(256) void gemm_kernel(
    const bf16* __restrict__ A, const bf16* __restrict__ BT,
    bf16* __restrict__ qo, bf16* __restrict__ ko, bf16* __restrict__ vto,
    const float* __restrict__ bias, float* __restrict__ fo) {
  constexpr int K = 512;
  __shared__ __align__(16) bf16 SMEM[128 * 136];   // staging (32KB) / transpose (34KB)
  bf16* As = SMEM;
  bf16* Bs = SMEM + 128 * 64;
  const int lane = threadIdx.x & 63;
  const int w = threadIdx.x >> 6;
  const int hi = lane >> 4;
  const int wm = w >> 1, wn = w & 1;
  const int m0 = blockIdx.y * 128, n0 = blockIdx.x * 128;
  const int sl = lane >> 3;                    // sub-row within 8-row chunk
  const int ssc = ((lane & 7) ^ sl) * 8;       // pre-swizzled source col (elems)

  f32x4 acc[4][4];
#pragma unroll
  for (int i = 0; i < 4; ++i)
#pragma unroll
    for (int j = 0; j < 4; ++j) acc[i][j] = {0.f, 0.f, 0.f, 0.f};

  for (int kt = 0; kt < K / 64; ++kt) {
    const int k0 = kt * 64;
    __syncthreads();
#pragma unroll
    for (int c = 0; c < 4; ++c) {
      const int ca = w * 4 + c;                // 16 x 1KB calls per tile
      const int trow = ca * 8 + sl;            // tile row this lane covers
      gload_lds16(A + (size_t)(m0 + trow) * K + k0 + ssc, As + ca * 512);
      gload_lds16(BT + (size_t)(n0 + trow) * K + k0 + ssc, Bs + ca * 512);
    }
    __syncthreads();
#pragma unroll
    for (int kc = 0; kc < 2; ++kc) {
      const int cs = kc * 4 + hi;              // k-slot 0..7
      const int csw = (cs ^ (lane & 7)) * 8;   // swizzled read col (elems)
      bf16x8 af[4], bfr[4];
#pragma unroll
      for (int mi = 0; mi < 4; ++mi)
        af[mi] = *reinterpret_cast<const bf16x8*>(
            &As[(wm * 64 + mi * 16 + (lane & 15)) * 64 + csw]);
#pragma unroll
      for (int ni = 0; ni < 4; ++ni)
        bfr[ni] = *reinterpret_cast<const bf16x8*>(
            &Bs[(wn * 64 + ni * 16 + (lane & 15)) * 64 + csw]);
#pragma unroll
      for (int mi = 0; mi < 4; ++mi)
#pragma unroll
        for (int ni = 0; ni < 4; ++ni)
          acc[mi][ni] = mfma16(af[mi], bfr[ni], acc[mi][ni]);
    }
  }

  if (EPI == 0 && n0 >= 1024) {
    // ---- V block: transpose via LDS, coalesced write to vto [bh][d][n] ----
    __syncthreads();                            // staging reads done, reuse SMEM
#pragma unroll
    for (int mi = 0; mi < 4; ++mi)
#pragma unroll
      for (int ni = 0; ni < 4; ++ni)
#pragma unroll
        for (int r = 0; r < 4; ++r) {
          const int rl = wm * 64 + mi * 16 + hi * 4 + r;        // local row (n)
          const int cl = wn * 64 + ni * 16 + (lane & 15);       // local col (d)
          SMEM[cl * 136 + rl] = (bf16)acc[mi][ni][r];
        }
    __syncthreads();
    const int b = m0 >> 12, nb = m0 & 4095;
    const int jj0 = n0 - 1024;
    const int cl = threadIdx.x >> 1, half = threadIdx.x & 1;
    const int jj = jj0 + cl, h = jj >> 6, d = jj & 63;
    bf16* dst = vto + ((size_t)(b * 8 + h) * 64 + d) * 4096 + nb + half * 64;
    const bf16* src = SMEM + cl * 136 + half * 64;
#pragma unroll
    for (int j = 0; j < 8; ++j)
      *reinterpret_cast<bf16x8*>(dst + j * 8) =
          *reinterpret_cast<const bf16x8*>(src + j * 8);
    return;
  }

#pragma unroll
  for (int mi = 0; mi < 4; ++mi) {
#pragma unroll
    for (int ni = 0; ni < 4; ++ni) {
#pragma unroll
      for (int r = 0; r < 4; ++r) {
        const int m = m0 + wm * 64 + mi * 16 + hi * 4 + r;
        const int col = n0 + wn * 64 + ni * 16 + (lane & 15);
        const float v = acc[mi][ni][r];
        if (EPI == 0) {
          const int b = m >> 12, n = m & 4095;
          const int sec = col >> 9, jj = col & 511, h = jj >> 6, d = jj & 63;
          const int bh = b * 8 + h;
          const bf16 hv = (bf16)v;
          if (sec == 0)
            qo[((size_t)bh * 4096 + n) * 64 + d] = hv;
          else
            ko[((size_t)bh * 4096 + n) * 64 + d] = hv;
        } else {
          fo[(size_t)m * 512 + col] = v + bias[col];
        }
      }
    }
  }
}

// ---------- fused relu-attention (round 5) ----------
// grid (16 q-tiles, 16 bh, 2 kv-halves). 4 waves/block; wave owns 64 q rows.
// K rows staged in sigma64 order -> S^T D-frag IS the PV A-frag after
// relu+pack (no P LDS round-trip, no cross-lane moves). V columns identity.
// 2-phase prefetch pipeline, raw barriers, vmcnt(0) after compute.
// scale deferred to the final O write (relu(s*c) = c*relu(s), c>0).
__global__ __launch_bounds__(256, 2) void attn_kernel(
    const bf16* __restrict__ Q, const bf16* __restrict__ Kg,
    const bf16* __restrict__ VT, float* __restrict__ out0,
    float* __restrict__ out1) {
  __shared__ __align__(16) bf16 Ks[2 * 64 * 64];   // dbuf [kv_phys][d] swizzled
  __shared__ __align__(16) bf16 Vs[2 * 64 * 64];   // dbuf [d][kv] swizzled
  const int lane = threadIdx.x & 63;
  const int w = threadIdx.x >> 6;
  const int hi = lane >> 4;
  const int ql = lane & 15;
  const int bh = blockIdx.y;
  const int q0 = blockIdx.x * 256 + w * 64;
  const int kvbase = blockIdx.z * 2048;
  const bf16* Qh = Q + (size_t)bh * 4096 * 64;
  const bf16* Kh = Kg + (size_t)bh * 4096 * 64;
  const bf16* Vh = VT + (size_t)bh * 64 * 4096;
  float* outp = blockIdx.z ? out1 : out0;

  const int sl = lane >> 3;
  const int ssc = ((lane & 7) ^ sl) * 8;           // pre-swizzled source col

  // per-chunk source offsets (kv0-invariant), K rows sigma-permuted
  int soff[4];
  if (w < 2) {
#pragma unroll
    for (int c = 0; c < 4; ++c) {
      const int rho = (w * 4 + c) * 8 + sl;        // physical LDS row
      soff[c] = sigma64(rho) * 64 + ssc;           // K global: row sigma(rho)
    }
  } else {
#pragma unroll
    for (int c = 0; c < 4; ++c) {
      const int d = ((w - 2) * 4 + c) * 8 + sl;    // VT row (d)
      soff[c] = d * 4096 + ssc;                    // V global: identity cols
    }
  }

  auto stage = [&](int bi, int kv0) {
    if (w < 2) {
      bf16* KsB = Ks + bi * 4096;
#pragma unroll
      for (int c = 0; c < 4; ++c)
        gload_lds16(Kh + (size_t)kv0 * 64 + soff[c], KsB + (w * 4 + c) * 512);
    } else {
      bf16* VsB = Vs + bi * 4096;
#pragma unroll
      for (int c = 0; c < 4; ++c)
        gload_lds16(Vh + kv0 + soff[c], VsB + ((w - 2) * 4 + c) * 512);
    }
  };

  bf16x8 qf[4][2];
#pragma unroll
  for (int qb = 0; qb < 4; ++qb)
#pragma unroll
    for (int kc = 0; kc < 2; ++kc)
      qf[qb][kc] = *reinterpret_cast<const bf16x8*>(
          &Qh[(size_t)(q0 + qb * 16 + ql) * 64 + kc * 32 + hi * 8]);

  f32x4 o[4][4];
#pragma unroll
  for (int qb = 0; qb < 4; ++qb)
#pragma unroll
    for (int db = 0; db < 4; ++db) o[qb][db] = {0.f, 0.f, 0.f, 0.f};

  // prologue: stage tile 0, wait, barrier
  stage(0, kvbase);
  asm volatile("s_waitcnt vmcnt(0)" ::: "memory");
  __builtin_amdgcn_s_barrier();

  for (int it = 0; it < 32; ++it) {
    const int kv0 = kvbase + it * 64;
    const int cur = it & 1;
    const bf16* KsC = Ks + cur * 4096;
    const bf16* VsC = Vs + cur * 4096;
    if (it < 31) stage(cur ^ 1, kv0 + 64);   // prefetch next tile

    // S^T = K_staged Q^T : s[qb][kvb], lane: col=q=ql, rows=phys kv
    f32x4 s[4][4];
#pragma unroll
    for (int qb = 0; qb < 4; ++qb)
#pragma unroll
      for (int kvb = 0; kvb < 4; ++kvb) s[qb][kvb] = {0.f, 0.f, 0.f, 0.f};
#pragma unroll
    for (int kc = 0; kc < 2; ++kc) {
      const int csw = ((kc * 4 + hi) ^ (lane & 7)) * 8;
      bf16x8 kf[4];
#pragma unroll
      for (int kvb = 0; kvb < 4; ++kvb)
        kf[kvb] = *reinterpret_cast<const bf16x8*>(
            &KsC[(kvb * 16 + ql) * 64 + csw]);
      __builtin_amdgcn_s_setprio(1);
#pragma unroll
      for (int qb = 0; qb < 4; ++qb)
#pragma unroll
        for (int kvb = 0; kvb < 4; ++kvb)
          s[qb][kvb] = mfma16(kf[kvb], qf[qb][kc], s[qb][kvb]);
      __builtin_amdgcn_s_setprio(0);
    }

    // PV: pack P in-register (sigma makes S^T frag == PV A-frag) and MFMA
#pragma unroll
    for (int kc = 0; kc < 2; ++kc) {
      const int csw = ((kc * 4 + hi) ^ (lane & 7)) * 8;
      bf16x8 vf[4];
#pragma unroll
      for (int db = 0; db < 4; ++db)
        vf[db] = *reinterpret_cast<const bf16x8*>(
            &VsC[(db * 16 + ql) * 64 + csw]);
      bf16x8 pa[4];
#pragma unroll
      for (int qb = 0; qb < 4; ++qb)
#pragma unroll
        for (int u = 0; u < 2; ++u)
#pragma unroll
          for (int r = 0; r < 4; ++r)
            pa[qb][u * 4 + r] = (bf16)fmaxf(s[qb][2 * kc + u][r], 0.f);
      __builtin_amdgcn_s_setprio(1);
#pragma unroll
      for (int qb = 0; qb < 4; ++qb)
#pragma unroll
        for (int db = 0; db < 4; ++db)
          o[qb][db] = mfma16(pa[qb], vf[db], o[qb][db]);
      __builtin_amdgcn_s_setprio(0);
    }

    // drain this iter's prefetch (latency covered by compute), flip
    asm volatile("s_waitcnt vmcnt(0)" ::: "memory");
    __builtin_amdgcn_s_barrier();
  }

  const int b = bh >> 3, h = bh & 7;
#pragma unroll
  for (int qb = 0; qb < 4; ++qb)
#pragma unroll
    for (int db = 0; db < 4; ++db)
#pragma unroll
      for (int r = 0; r < 4; ++r) {
        const int n = q0 + qb * 16 + hi * 4 + r;
        const int dcol = db * 16 + ql;
        outp[((size_t)(b * 4096 + n)) * 512 + h * 64 + dcol] = o[qb][db][r] * 0.125f;
      }
}

// ---------- LayerNorm over 512 of (in0+in1), one wave per row, bf16 out ----------
__global__ __launch_bounds__(256) void ln_kernel(const float* __restrict__ in0,
                                                 const float* __restrict__ in1,
                                                 const float* __restrict__ gamma,
                                                 const float* __restrict__ beta,
                                                 bf16* __restrict__ out) {
  const int lane = threadIdx.x & 63;
  const int w = threadIdx.x >> 6;
  const int row = blockIdx.x * 4 + w;
  const float* r0 = in0 + (size_t)row * 512;
  const float* r1 = in1 + (size_t)row * 512;
  f32x4 a = *reinterpret_cast<const f32x4*>(&r0[lane * 4]);
  f32x4 b = *reinterpret_cast<const f32x4*>(&r0[256 + lane * 4]);
  f32x4 a1 = *reinterpret_cast<const f32x4*>(&r1[lane * 4]);
  f32x4 b1 = *reinterpret_cast<const f32x4*>(&r1[256 + lane * 4]);
#pragma unroll
  for (int i = 0; i < 4; ++i) { a[i] += a1[i]; b[i] += b1[i]; }
  float s = a[0] + a[1] + a[2] + a[3] + b[0] + b[1] + b[2] + b[3];
  float ss = a[0] * a[0] + a[1] * a[1] + a[2] * a[2] + a[3] * a[3] +
             b[0] * b[0] + b[1] * b[1] + b[2] * b[2] + b[3] * b[3];
#pragma unroll
  for (int off = 32; off > 0; off >>= 1) {
    s += __shfl_xor(s, off);
    ss += __shfl_xor(ss, off);
  }
  const float mean = s * (1.f / 512.f);
  const float var = ss * (1.f / 512.f) - mean * mean;
  const float rstd = rsqrtf(var + 1e-5f);
  f32x4 g0 = *reinterpret_cast<const f32x4*>(&gamma[lane * 4]);
  f32x4 g1 = *reinterpret_cast<const f32x4*>(&gamma[256 + lane * 4]);
  f32x4 e0 = *reinterpret_cast<const f32x4*>(&beta[lane * 4]);
  f32x4 e1 = *reinterpret_cast<const f32x4*>(&beta[256 + lane * 4]);
  bf16x4 o0, o1;
#pragma unroll
  for (int i = 0; i < 4; ++i) {
    o0[i] = (bf16)((a[i] - mean) * rstd * g0[i] + e0[i]);
    o1[i] = (bf16)((b[i] - mean) * rstd * g1[i] + e1[i]);
  }
  *reinterpret_cast<bf16x4*>(&out[(size_t)row * 512 + lane * 4]) = o0;
  *reinterpret_cast<bf16x4*>(&out[(size_t)row * 512 + 256 + lane * 4]) = o1;
}

extern "C" void kernel_launch(void* const* d_in, const int* in_sizes, int n_in,
                              void* d_out, int out_size, void* d_ws, size_t ws_size,
                              hipStream_t stream) {
  const float* x = (const float*)d_in[0];       // [2,4096,512]
  const float* w_qkv = (const float*)d_in[1];   // [512,1536]
  const float* ln_g = (const float*)d_in[2];    // [512]
  const float* ln_b = (const float*)d_in[3];    // [512]
  const float* w_out = (const float*)d_in[4];   // [512,512]
  const float* b_out = (const float*)d_in[5];   // [512]
  float* out = (float*)d_out;                   // [2,4096,512] f32

  char* ws = (char*)d_ws;
  size_t off = 0;
  auto alloc = [&](size_t bytes) {
    void* p = ws + off;
    off += (bytes + 255) & ~(size_t)255;
    return p;
  };
  bf16* x_bf = (bf16*)alloc((size_t)8192 * 512 * 2);
  bf16* wqkvT = (bf16*)alloc((size_t)1536 * 512 * 2);
  bf16* woutT = (bf16*)alloc((size_t)512 * 512 * 2);
  bf16* qbuf = (bf16*)alloc((size_t)16 * 4096 * 64 * 2);
  bf16* kbuf = (bf16*)alloc((size_t)16 * 4096 * 64 * 2);
  bf16* vtbuf = (bf16*)alloc((size_t)16 * 64 * 4096 * 2);
  float* attn_out0 = (float*)alloc((size_t)8192 * 512 * 4);
  float* attn_out1 = (float*)alloc((size_t)8192 * 512 * 4);
  bf16* ln_bf = (bf16*)alloc((size_t)8192 * 512 * 2);

  // 1) converts
  cvt_kernel<<<2048, 256, 0, stream>>>(x, x_bf, 8192 * 512 / 4);
  tcvt_kernel<<<1024, 256, 0, stream>>>(w_qkv, wqkvT, 512, 1536);
  tcvt_kernel<<<512, 256, 0, stream>>>(w_out, woutT, 512, 512);

  // 2) qkv = x @ w_qkv -> Q,K (row-major per head), V transposed [d][n]
  gemm_kernel<0><<<dim3(12, 64), 256, 0, stream>>>(x_bf, wqkvT, qbuf, kbuf, vtbuf,
                                                   nullptr, nullptr);

  // 3) fused relu-attention -> two partial f32 buffers (kv-split halves)
  attn_kernel<<<dim3(16, 16, 2), 256, 0, stream>>>(qbuf, kbuf, vtbuf,
                                                   attn_out0, attn_out1);

  // 4) layernorm(sum of halves) -> bf16
  ln_kernel<<<2048, 256, 0, stream>>>(attn_out0, attn_out1, ln_g, ln_b, ln_bf);

  // 5) out = ln @ w_out + b_out -> f32
  gemm_kernel<1><<<dim3(4, 64), 256, 0, stream>>>(ln_bf, woutT, nullptr, nullptr,
                                                  nullptr, b_out, out);
}

// Round 6
// 182.463 us; speedup vs baseline: 1.5691x; 1.0502x over previous
//
#include <hip/hip_runtime.h>
#include <stdint.h>
#include <stddef.h>

typedef __bf16 bf16;
typedef bf16 bf16x4 __attribute__((ext_vector_type(4)));
typedef bf16 bf16x8 __attribute__((ext_vector_type(8)));
typedef float f32x4 __attribute__((ext_vector_type(4)));

#define DEVI static __device__ __forceinline__

// B=2, N=4096, DIM=512, HEADS=8, DHEAD=64, INNER=512

DEVI f32x4 mfma16(bf16x8 a, bf16x8 b, f32x4 c) {
  return __builtin_amdgcn_mfma_f32_16x16x32_bf16(a, b, c, 0, 0, 0);
}

DEVI void gload_lds16(const bf16* g, bf16* lds) {
  __builtin_amdgcn_global_load_lds(
      (const __attribute__((address_space(1))) unsigned int*)g,
      (__attribute__((address_space(3))) unsigned int*)lds, 16, 0, 0);
}

// kv bit-permutation for in-register P:
// sigma(32kc+16u+4hi+r) = 32kc+8hi+4u+r.  S^T computed against K rows staged
// in sigma order makes the S^T D-fragment coincide with the PV A-fragment.
DEVI int sigma64(int r) { return (r & 0x23) | ((r & 0xC) << 1) | ((r & 0x10) >> 2); }

// LDS tiles are [R][64] bf16 (128 B rows). XOR-swizzle involution on 16B
// granules (slots of 8 elems): slot' = slot ^ (row&7).
// global_load_lds writes linearly (LDS slot = lane&7, row = base+lane>>3), so
// the SOURCE column slot is pre-swizzled: src_slot = (lane&7) ^ (row&7).
// Every read of logical slot cs fetches LDS slot cs ^ (row&7). All fragment
// rows have row&7 == lane&7, so reads are conflict-free (rule #21 / T2).
// Fragment k-slot for 16x16x32: cs = kc*4 + (lane>>4).

// ---------- f32 -> bf16 convert (vectorized) ----------
__global__ __launch_bounds__(256) void cvt_kernel(const float* __restrict__ in,
                                                  bf16* __restrict__ out, int n4) {
  int i = blockIdx.x * blockDim.x + threadIdx.x;
  const int stride = gridDim.x * blockDim.x;
  for (; i < n4; i += stride) {
    f32x4 v = reinterpret_cast<const f32x4*>(in)[i];
    bf16x4 o;
    o[0] = (bf16)v[0]; o[1] = (bf16)v[1]; o[2] = (bf16)v[2]; o[3] = (bf16)v[3];
    reinterpret_cast<bf16x4*>(out)[i] = o;
  }
}

// ---------- transpose-convert via LDS: in [K][N] f32 -> out [N][K] bf16 ----
// 64x64 tile; grid (Nd/64, Kd/64). Coalesced reads, vectorized 16B writes.
__global__ __launch_bounds__(256) void tcvt_kernel(const float* __restrict__ in,
                                                   bf16* __restrict__ out, int Kd, int Nd) {
  __shared__ bf16 T[64 * 80];
  const int k0 = blockIdx.y * 64, n0 = blockIdx.x * 64;
  const int r = threadIdx.x >> 2;
  const int c0 = (threadIdx.x & 3) * 16;
  const float* src = in + (size_t)(k0 + r) * Nd + n0 + c0;
#pragma unroll
  for (int j = 0; j < 16; ++j) T[(c0 + j) * 80 + r] = (bf16)src[j];
  __syncthreads();
  bf16* dst = out + (size_t)(n0 + r) * Kd + k0 + c0;
  const bf16* s = T + r * 80 + c0;
#pragma unroll
  for (int j = 0; j < 2; ++j)
    *reinterpret_cast<bf16x8*>(dst + j * 8) =
        *reinterpret_cast<const bf16x8*>(s + j * 8);
}

// ---------- GEMM: A[M][512] bf16 row-major, BT[N][512] bf16 row-major ----------
// 128x128 tile, BK=64, 2-phase dbuf prefetch (raw barriers, vmcnt(0) after
// compute), 4 waves (2x2), each wave 64x64 = 4x4 frags of 16x16x32.
// EPI 0: epilogue via LDS: Q,K row-major 16B stores; V transposed 16B stores.
// EPI 1: out f32 [M][512] = acc + bias[col] (output projection).
template <int EPI>
__global__ __launch_bounds__(256) void gemm_kernel(
    const bf16* __restrict__ A, const bf16* __restrict__ BT,
    bf16* __restrict__ qo, bf16* __restrict__ ko, bf16* __restrict__ vto,
    const float* __restrict__ bias, float* __restrict__ fo) {
  constexpr int K = 512;
  __shared__ __align__(16) bf16 SM[4 * 128 * 64];   // 64 KB: dbuf A/B + epilogue
  const int lane = threadIdx.x & 63;
  const int w = threadIdx.x >> 6;
  const int hi = lane >> 4;
  const int wm = w >> 1, wn = w & 1;
  const int m0 = blockIdx.y * 128, n0 = blockIdx.x * 128;
  const int sl = lane >> 3;                    // sub-row within 8-row chunk
  const int ssc = ((lane & 7) ^ sl) * 8;       // pre-swizzled source col (elems)

  auto AsB = [&](int bi) { return SM + bi * 8192; };
  auto BsB = [&](int bi) { return SM + 16384 + bi * 8192; };

  auto stage = [&](int bi, int kt) {
    const int k0 = kt * 64;
#pragma unroll
    for (int c = 0; c < 4; ++c) {
      const int ca = w * 4 + c;                // 16 x 1KB calls per tile
      const int trow = ca * 8 + sl;            // tile row this lane covers
      gload_lds16(A + (size_t)(m0 + trow) * K + k0 + ssc, AsB(bi) + ca * 512);
      gload_lds16(BT + (size_t)(n0 + trow) * K + k0 + ssc, BsB(bi) + ca * 512);
    }
  };

  f32x4 acc[4][4];
#pragma unroll
  for (int i = 0; i < 4; ++i)
#pragma unroll
    for (int j = 0; j < 4; ++j) acc[i][j] = {0.f, 0.f, 0.f, 0.f};

  stage(0, 0);
  asm volatile("s_waitcnt vmcnt(0)" ::: "memory");
  __builtin_amdgcn_s_barrier();

  for (int kt = 0; kt < K / 64; ++kt) {
    const int cur = kt & 1;
    if (kt < K / 64 - 1) stage(cur ^ 1, kt + 1);
    const bf16* As = AsB(cur);
    const bf16* Bs = BsB(cur);
#pragma unroll
    for (int kc = 0; kc < 2; ++kc) {
      const int cs = kc * 4 + hi;              // k-slot 0..7
      const int csw = (cs ^ (lane & 7)) * 8;   // swizzled read col (elems)
      bf16x8 af[4], bfr[4];
#pragma unroll
      for (int mi = 0; mi < 4; ++mi)
        af[mi] = *reinterpret_cast<const bf16x8*>(
            &As[(wm * 64 + mi * 16 + (lane & 15)) * 64 + csw]);
#pragma unroll
      for (int ni = 0; ni < 4; ++ni)
        bfr[ni] = *reinterpret_cast<const bf16x8*>(
            &Bs[(wn * 64 + ni * 16 + (lane & 15)) * 64 + csw]);
      __builtin_amdgcn_s_setprio(1);
#pragma unroll
      for (int mi = 0; mi < 4; ++mi)
#pragma unroll
        for (int ni = 0; ni < 4; ++ni)
          acc[mi][ni] = mfma16(af[mi], bfr[ni], acc[mi][ni]);
      __builtin_amdgcn_s_setprio(0);
    }
    asm volatile("s_waitcnt vmcnt(0)" ::: "memory");
    __builtin_amdgcn_s_barrier();
  }

  if (EPI == 0) {
    // ---- epilogue via LDS (SM free after final barrier) ----
    if (n0 < 1024) {
      // Q/K blocks: row-major SM[m][col], then 16B-vector row stores
#pragma unroll
      for (int mi = 0; mi < 4; ++mi)
#pragma unroll
        for (int ni = 0; ni < 4; ++ni)
#pragma unroll
          for (int r = 0; r < 4; ++r) {
            const int rl = wm * 64 + mi * 16 + hi * 4 + r;
            const int cl = wn * 64 + ni * 16 + (lane & 15);
            SM[rl * 136 + cl] = (bf16)acc[mi][ni][r];
          }
      __syncthreads();
      const int rl = threadIdx.x >> 1, hh = threadIdx.x & 1;
      const int m = m0 + rl, b = m >> 12, n = m & 4095;
      const int colg = n0 + hh * 64;
      const int sec = colg >> 9, h = (colg & 511) >> 6;
      bf16* dst = (sec ? ko : qo) + ((size_t)(b * 8 + h) * 4096 + n) * 64;
      const bf16* srcp = SM + rl * 136 + hh * 64;
#pragma unroll
      for (int j = 0; j < 8; ++j)
        *reinterpret_cast<bf16x8*>(dst + j * 8) =
            *reinterpret_cast<const bf16x8*>(srcp + j * 8);
    } else {
      // V blocks: transpose via SM, coalesced write to vto [bh][d][n]
#pragma unroll
      for (int mi = 0; mi < 4; ++mi)
#pragma unroll
        for (int ni = 0; ni < 4; ++ni)
#pragma unroll
          for (int r = 0; r < 4; ++r) {
            const int rl = wm * 64 + mi * 16 + hi * 4 + r;      // local row (n)
            const int cl = wn * 64 + ni * 16 + (lane & 15);     // local col (d)
            SM[cl * 136 + rl] = (bf16)acc[mi][ni][r];
          }
      __syncthreads();
      const int b = m0 >> 12, nb = m0 & 4095;
      const int cl = threadIdx.x >> 1, half = threadIdx.x & 1;
      const int jj = (n0 - 1024) + cl, h = jj >> 6, d = jj & 63;
      bf16* dst = vto + ((size_t)(b * 8 + h) * 64 + d) * 4096 + nb + half * 64;
      const bf16* srcp = SM + cl * 136 + half * 64;
#pragma unroll
      for (int j = 0; j < 8; ++j)
        *reinterpret_cast<bf16x8*>(dst + j * 8) =
            *reinterpret_cast<const bf16x8*>(srcp + j * 8);
    }
    return;
  }

#pragma unroll
  for (int mi = 0; mi < 4; ++mi) {
#pragma unroll
    for (int ni = 0; ni < 4; ++ni) {
#pragma unroll
      for (int r = 0; r < 4; ++r) {
        const int m = m0 + wm * 64 + mi * 16 + hi * 4 + r;
        const int col = n0 + wn * 64 + ni * 16 + (lane & 15);
        fo[(size_t)m * 512 + col] = acc[mi][ni][r] + bias[col];
      }
    }
  }
}

// ---------- fused relu-attention (round 6) ----------
// grid (32 q-tiles, 16 bh, 2 kv-halves). 4 waves/block; wave owns 32 q rows.
// 1024 blocks = 4 blocks/CU = 16 waves/CU (was 2 blocks/CU round 5).
// K rows staged in sigma64 order -> S^T D-frag IS the PV A-frag after
// relu+pack (no P LDS round-trip). 2-phase prefetch, raw barriers.
// scale deferred to the final O write (relu(s*c) = c*relu(s), c>0).
__global__ __launch_bounds__(256, 4) void attn_kernel(
    const bf16* __restrict__ Q, const bf16* __restrict__ Kg,
    const bf16* __restrict__ VT, float* __restrict__ out0,
    float* __restrict__ out1) {
  __shared__ __align__(16) bf16 Ks[2 * 64 * 64];   // dbuf [kv_phys][d] swizzled
  __shared__ __align__(16) bf16 Vs[2 * 64 * 64];   // dbuf [d][kv] swizzled
  const int lane = threadIdx.x & 63;
  const int w = threadIdx.x >> 6;
  const int hi = lane >> 4;
  const int ql = lane & 15;
  const int bh = blockIdx.y;
  const int q0 = blockIdx.x * 128 + w * 32;
  const int kvbase = blockIdx.z * 2048;
  const bf16* Qh = Q + (size_t)bh * 4096 * 64;
  const bf16* Kh = Kg + (size_t)bh * 4096 * 64;
  const bf16* Vh = VT + (size_t)bh * 64 * 4096;
  float* outp = blockIdx.z ? out1 : out0;

  const int sl = lane >> 3;
  const int ssc = ((lane & 7) ^ sl) * 8;           // pre-swizzled source col

  // per-chunk source offsets (kv0-invariant), K rows sigma-permuted
  int soff[4];
  if (w < 2) {
#pragma unroll
    for (int c = 0; c < 4; ++c) {
      const int rho = (w * 4 + c) * 8 + sl;        // physical LDS row
      soff[c] = sigma64(rho) * 64 + ssc;           // K global: row sigma(rho)
    }
  } else {
#pragma unroll
    for (int c = 0; c < 4; ++c) {
      const int d = ((w - 2) * 4 + c) * 8 + sl;    // VT row (d)
      soff[c] = d * 4096 + ssc;                    // V global: identity cols
    }
  }

  auto stage = [&](int bi, int kv0) {
    if (w < 2) {
      bf16* KsB = Ks + bi * 4096;
#pragma unroll
      for (int c = 0; c < 4; ++c)
        gload_lds16(Kh + (size_t)kv0 * 64 + soff[c], KsB + (w * 4 + c) * 512);
    } else {
      bf16* VsB = Vs + bi * 4096;
#pragma unroll
      for (int c = 0; c < 4; ++c)
        gload_lds16(Vh + kv0 + soff[c], VsB + ((w - 2) * 4 + c) * 512);
    }
  };

  bf16x8 qf[2][2];
#pragma unroll
  for (int qb = 0; qb < 2; ++qb)
#pragma unroll
    for (int kc = 0; kc < 2; ++kc)
      qf[qb][kc] = *reinterpret_cast<const bf16x8*>(
          &Qh[(size_t)(q0 + qb * 16 + ql) * 64 + kc * 32 + hi * 8]);

  f32x4 o[2][4];
#pragma unroll
  for (int qb = 0; qb < 2; ++qb)
#pragma unroll
    for (int db = 0; db < 4; ++db) o[qb][db] = {0.f, 0.f, 0.f, 0.f};

  // prologue: stage tile 0, wait, barrier
  stage(0, kvbase);
  asm volatile("s_waitcnt vmcnt(0)" ::: "memory");
  __builtin_amdgcn_s_barrier();

  for (int it = 0; it < 32; ++it) {
    const int kv0 = kvbase + it * 64;
    const int cur = it & 1;
    const bf16* KsC = Ks + cur * 4096;
    const bf16* VsC = Vs + cur * 4096;
    if (it < 31) stage(cur ^ 1, kv0 + 64);   // prefetch next tile

    // S^T = K_staged Q^T : s[qb][kvb], lane: col=q=ql, rows=phys kv
    f32x4 s[2][4];
#pragma unroll
    for (int qb = 0; qb < 2; ++qb)
#pragma unroll
      for (int kvb = 0; kvb < 4; ++kvb) s[qb][kvb] = {0.f, 0.f, 0.f, 0.f};
#pragma unroll
    for (int kc = 0; kc < 2; ++kc) {
      const int csw = ((kc * 4 + hi) ^ (lane & 7)) * 8;
      bf16x8 kf[4];
#pragma unroll
      for (int kvb = 0; kvb < 4; ++kvb)
        kf[kvb] = *reinterpret_cast<const bf16x8*>(
            &KsC[(kvb * 16 + ql) * 64 + csw]);
      __builtin_amdgcn_s_setprio(1);
#pragma unroll
      for (int qb = 0; qb < 2; ++qb)
#pragma unroll
        for (int kvb = 0; kvb < 4; ++kvb)
          s[qb][kvb] = mfma16(kf[kvb], qf[qb][kc], s[qb][kvb]);
      __builtin_amdgcn_s_setprio(0);
    }

    // PV: pack P in-register (sigma makes S^T frag == PV A-frag) and MFMA
#pragma unroll
    for (int kc = 0; kc < 2; ++kc) {
      const int csw = ((kc * 4 + hi) ^ (lane & 7)) * 8;
      bf16x8 vf[4];
#pragma unroll
      for (int db = 0; db < 4; ++db)
        vf[db] = *reinterpret_cast<const bf16x8*>(
            &VsC[(db * 16 + ql) * 64 + csw]);
      bf16x8 pa[2];
#pragma unroll
      for (int qb = 0; qb < 2; ++qb)
#pragma unroll
        for (int u = 0; u < 2; ++u)
#pragma unroll
          for (int r = 0; r < 4; ++r)
            pa[qb][u * 4 + r] = (bf16)fmaxf(s[qb][2 * kc + u][r], 0.f);
      __builtin_amdgcn_s_setprio(1);
#pragma unroll
      for (int qb = 0; qb < 2; ++qb)
#pragma unroll
        for (int db = 0; db < 4; ++db)
          o[qb][db] = mfma16(pa[qb], vf[db], o[qb][db]);
      __builtin_amdgcn_s_setprio(0);
    }

    // drain this iter's prefetch (latency covered by compute), flip
    asm volatile("s_waitcnt vmcnt(0)" ::: "memory");
    __builtin_amdgcn_s_barrier();
  }

  const int b = bh >> 3, h = bh & 7;
#pragma unroll
  for (int qb = 0; qb < 2; ++qb)
#pragma unroll
    for (int db = 0; db < 4; ++db)
#pragma unroll
      for (int r = 0; r < 4; ++r) {
        const int n = q0 + qb * 16 + hi * 4 + r;
        const int dcol = db * 16 + ql;
        outp[((size_t)(b * 4096 + n)) * 512 + h * 64 + dcol] = o[qb][db][r] * 0.125f;
      }
}

// ---------- LayerNorm over 512 of (in0+in1), one wave per row, bf16 out ----------
__global__ __launch_bounds__(256) void ln_kernel(const float* __restrict__ in0,
                                                 const float* __restrict__ in1,
                                                 const float* __restrict__ gamma,
                                                 const float* __restrict__ beta,
                                                 bf16* __restrict__ out) {
  const int lane = threadIdx.x & 63;
  const int w = threadIdx.x >> 6;
  const int row = blockIdx.x * 4 + w;
  const float* r0 = in0 + (size_t)row * 512;
  const float* r1 = in1 + (size_t)row * 512;
  f32x4 a = *reinterpret_cast<const f32x4*>(&r0[lane * 4]);
  f32x4 b = *reinterpret_cast<const f32x4*>(&r0[256 + lane * 4]);
  f32x4 a1 = *reinterpret_cast<const f32x4*>(&r1[lane * 4]);
  f32x4 b1 = *reinterpret_cast<const f32x4*>(&r1[256 + lane * 4]);
#pragma unroll
  for (int i = 0; i < 4; ++i) { a[i] += a1[i]; b[i] += b1[i]; }
  float s = a[0] + a[1] + a[2] + a[3] + b[0] + b[1] + b[2] + b[3];
  float ss = a[0] * a[0] + a[1] * a[1] + a[2] * a[2] + a[3] * a[3] +
             b[0] * b[0] + b[1] * b[1] + b[2] * b[2] + b[3] * b[3];
#pragma unroll
  for (int off = 32; off > 0; off >>= 1) {
    s += __shfl_xor(s, off);
    ss += __shfl_xor(ss, off);
  }
  const float mean = s * (1.f / 512.f);
  const float var = ss * (1.f / 512.f) - mean * mean;
  const float rstd = rsqrtf(var + 1e-5f);
  f32x4 g0 = *reinterpret_cast<const f32x4*>(&gamma[lane * 4]);
  f32x4 g1 = *reinterpret_cast<const f32x4*>(&gamma[256 + lane * 4]);
  f32x4 e0 = *reinterpret_cast<const f32x4*>(&beta[lane * 4]);
  f32x4 e1 = *reinterpret_cast<const f32x4*>(&beta[256 + lane * 4]);
  bf16x4 o0, o1;
#pragma unroll
  for (int i = 0; i < 4; ++i) {
    o0[i] = (bf16)((a[i] - mean) * rstd * g0[i] + e0[i]);
    o1[i] = (bf16)((b[i] - mean) * rstd * g1[i] + e1[i]);
  }
  *reinterpret_cast<bf16x4*>(&out[(size_t)row * 512 + lane * 4]) = o0;
  *reinterpret_cast<bf16x4*>(&out[(size_t)row * 512 + 256 + lane * 4]) = o1;
}

extern "C" void kernel_launch(void* const* d_in, const int* in_sizes, int n_in,
                              void* d_out, int out_size, void* d_ws, size_t ws_size,
                              hipStream_t stream) {
  const float* x = (const float*)d_in[0];       // [2,4096,512]
  const float* w_qkv = (const float*)d_in[1];   // [512,1536]
  const float* ln_g = (const float*)d_in[2];    // [512]
  const float* ln_b = (const float*)d_in[3];    // [512]
  const float* w_out = (const float*)d_in[4];   // [512,512]
  const float* b_out = (const float*)d_in[5];   // [512]
  float* out = (float*)d_out;                   // [2,4096,512] f32

  char* ws = (char*)d_ws;
  size_t off = 0;
  auto alloc = [&](size_t bytes) {
    void* p = ws + off;
    off += (bytes + 255) & ~(size_t)255;
    return p;
  };
  bf16* x_bf = (bf16*)alloc((size_t)8192 * 512 * 2);
  bf16* wqkvT = (bf16*)alloc((size_t)1536 * 512 * 2);
  bf16* woutT = (bf16*)alloc((size_t)512 * 512 * 2);
  bf16* qbuf = (bf16*)alloc((size_t)16 * 4096 * 64 * 2);
  bf16* kbuf = (bf16*)alloc((size_t)16 * 4096 * 64 * 2);
  bf16* vtbuf = (bf16*)alloc((size_t)16 * 64 * 4096 * 2);
  float* attn_out0 = (float*)alloc((size_t)8192 * 512 * 4);
  float* attn_out1 = (float*)alloc((size_t)8192 * 512 * 4);
  bf16* ln_bf = (bf16*)alloc((size_t)8192 * 512 * 2);

  // 1) converts
  cvt_kernel<<<2048, 256, 0, stream>>>(x, x_bf, 8192 * 512 / 4);
  tcvt_kernel<<<dim3(24, 8), 256, 0, stream>>>(w_qkv, wqkvT, 512, 1536);
  tcvt_kernel<<<dim3(8, 8), 256, 0, stream>>>(w_out, woutT, 512, 512);

  // 2) qkv = x @ w_qkv -> Q,K (row-major per head), V transposed [d][n]
  gemm_kernel<0><<<dim3(12, 64), 256, 0, stream>>>(x_bf, wqkvT, qbuf, kbuf, vtbuf,
                                                   nullptr, nullptr);

  // 3) fused relu-attention -> two partial f32 buffers (kv-split halves)
  attn_kernel<<<dim3(32, 16, 2), 256, 0, stream>>>(qbuf, kbuf, vtbuf,
                                                   attn_out0, attn_out1);

  // 4) layernorm(sum of halves) -> bf16
  ln_kernel<<<2048, 256, 0, stream>>>(attn_out0, attn_out1, ln_g, ln_b, ln_bf);

  // 5) out = ln @ w_out + b_out -> f32
  gemm_kernel<1><<<dim3(4, 64), 256, 0, stream>>>(ln_bf, woutT, nullptr, nullptr,
                                                  nullptr, b_out, out);
}